// Round 10
// baseline (238.980 us; speedup 1.0000x reference)
//
#include <hip/hip_runtime.h>
#include <hip/hip_bf16.h>
#include <hip/hip_fp16.h>

// Bahdanau location-sensitive attention, fused f16-MFMA implementation.
// R10: m97 geometry — 128x128 tile, 256 thr / 4 waves, BK=64, single-buffered
//      2-barrier loop, BOTH operands global_load_lds (A as f32 32KB, B f16 16KB,
//      51KB LDS -> 3 blocks/CU). Read-side f32->f16 cvt on A fragments.
//      3 independent 4-wave barrier groups per CU = the TLP regime that m97
//      proved (874 TF); our 512-thread designs never had it.
// B=32 T=1536 H=1024 CTX=1024 CONV_OUT=32

constexpr int kB = 32, kT = 1536, kH = 1024, kC = 1024, kCO = 32;
constexpr int kM = kB * kT;      // 49152
constexpr int kKb = 1088;        // padded B K: 1024 V | 32 U | 32 zero

typedef _Float16 f16;
typedef _Float16 f16x8 __attribute__((ext_vector_type(8)));
typedef float f32x4 __attribute__((ext_vector_type(4)));

// ---- ws layout (bytes) ----
constexpr size_t WS_B     = 0;                                   // kC*kKb f16  (2.2 MB)
constexpr size_t WS_LOC   = WS_B + (size_t)kC * kKb * 2;         // kM*64 f16   (6.3 MB)
constexpr size_t WS_ADD   = WS_LOC + (size_t)kM * 64 * 2;        // kB*kC f32
constexpr size_t WS_SCORE = WS_ADD + (size_t)kB * kC * 4;        // 8*kM f32 partial scores
constexpr size_t WS_CTXP  = WS_SCORE + (size_t)8 * kM * 4;       // 8*kB*kH f32

__device__ __forceinline__ void gload16(const void* g, void* l) {
    __builtin_amdgcn_global_load_lds(
        (const __attribute__((address_space(1))) void*)g,
        (__attribute__((address_space(3))) void*)l, 16, 0, 0);
}

// ---------------------------------------------------------------- B pack [kC][1088] f16
__global__ void k_prep_b2(const float* __restrict__ V, const float* __restrict__ U,
                          f16* __restrict__ Bf) {
    int c = blockIdx.x;
    for (int k = threadIdx.x; k < kKb; k += 256) {
        float v = (k < kH) ? V[(size_t)c * kH + k]
                : (k < kH + kCO) ? U[(size_t)c * kCO + (k - kH)] : 0.f;
        Bf[(size_t)c * kKb + k] = (f16)v;
    }
}

// ---------------------------------------------------------------- conv1d -> locPad [M][64] f16 (cols 0..31 real)
__global__ void k_loc(const float* __restrict__ la, const float* __restrict__ cw,
                      const float* __restrict__ cb, f16* __restrict__ locPad) {
    int m = blockIdx.x * 256 + threadIdx.x;          // < kM
    int b = m / kT, t = m - b * kT;
    float x0 = (t > 0)      ? la[(size_t)b * kT + t - 1] : 0.f;
    float x1 = la[(size_t)b * kT + t];
    float x2 = (t < kT - 1) ? la[(size_t)b * kT + t + 1] : 0.f;
    union { f16 h[32]; int4 q[4]; } u;
#pragma unroll
    for (int k = 0; k < 32; ++k)
        u.h[k] = (f16)(cw[k * 3] * x0 + cw[k * 3 + 1] * x1 + cw[k * 3 + 2] * x2 + cb[k]);
    int4* dst = (int4*)(locPad + (size_t)m * 64);
    dst[0] = u.q[0]; dst[1] = u.q[1]; dst[2] = u.q[2]; dst[3] = u.q[3];
    // cols 32..63: staged to LDS in the tail but never read (tail K=32)
}

// ---------------------------------------------------------------- prep add = dec@W^T + bias
__global__ void k_prep_add(const float* __restrict__ dec, const float* __restrict__ W,
                           const float* __restrict__ bias, float* __restrict__ add) {
    __shared__ float dl[kH];
    int bb = blockIdx.x >> 2;
    int cc = (blockIdx.x & 3) * 256 + threadIdx.x;
    *(float4*)&dl[threadIdx.x * 4] = *(const float4*)&dec[(size_t)bb * kH + threadIdx.x * 4];
    __syncthreads();
    float acc = bias[cc];
    const float* wr = W + (size_t)cc * kH;
    for (int h = 0; h < kH; h += 4) {
        float4 wv = *(const float4*)&wr[h];
        acc += wv.x * dl[h] + wv.y * dl[h + 1] + wv.z * dl[h + 2] + wv.w * dl[h + 3];
    }
    add[(size_t)bb * kC + cc] = acc;
}

// ---------------------------------------------------------------- fused main GEMM
// Tile 128(M) x 128(N), BK=64, 256 thr = 4 waves (2M x 2N), per-wave 64x64.
// LDS (51200 B): As f32 [128 rows][16 chunks 16B, phys = c ^ (row&15)] @0 (32 KB);
//   Bs f16 [128 rows][8 chunks, phys = c ^ (row&7)] @32768 (16 KB);
//   add_l @49152 (128 f32); w_l @49664; sred @50176 ([2][64][2] f32).
// 3 blocks/CU: three independent 4-wave barrier groups hide each other's
// stage drains (m97 regime). Read-side cvt f32->f16 overlaps the MFMA pipe.
__launch_bounds__(256, 3)
__global__ void k_main(const float* __restrict__ enc, const f16* __restrict__ Bf,
                       const f16* __restrict__ locPad, const float* __restrict__ add,
                       const float* __restrict__ wvec, float* __restrict__ spart) {
    __shared__ __align__(16) char smem[51200];
    float* add_l = (float*)(smem + 49152);
    float* w_l   = (float*)(smem + 49664);
    float (*sred)[64][2] = (float (*)[64][2])(smem + 50176);

    const int tid = threadIdx.x, lane = tid & 63, wave = tid >> 6;
    const int wm = wave >> 1, wn = wave & 1;
    // bijective XCD swizzle: 3072 blocks = 8 XCDs x 384; nt fastest (8 per A strip)
    const int raw = blockIdx.x;
    const int lin = (raw & 7) * 384 + (raw >> 3);
    const int mt = lin >> 3, nt = lin & 7;
    const int m0 = mt * 128, n0 = nt * 128;
    const int bb = m0 / kT;                          // 128 | 1536

    if (tid < 128) {
        add_l[tid] = add[(size_t)bb * kC + n0 + tid];
        w_l[tid]   = wvec[n0 + tid];
    }

    f32x4 acc[4][4];
#pragma unroll
    for (int i = 0; i < 4; ++i)
#pragma unroll
        for (int j = 0; j < 4; ++j) acc[i][j] = (f32x4){0.f, 0.f, 0.f, 0.f};

    // A staging (f32): 8 gloads/thread, each covers 4 rows x 256B.
    // lane: row_in = l>>4, phys chunk = l&15; src chunk = (l&15) ^ (row&15).
    const int rA = lane >> 4;
    const float* aS[8];
#pragma unroll
    for (int j = 0; j < 8; ++j) {
        int row = wave * 32 + j * 4 + rA;
        int gc = (lane & 15) ^ (row & 15);
        aS[j] = enc + (size_t)(m0 + row) * kH + gc * 4;
    }
    // B staging (f16): 4 gloads/thread, each covers 8 rows x 128B.
    const int rB = lane >> 3;
    const f16* bS[4];
#pragma unroll
    for (int j = 0; j < 4; ++j) {
        int row = wave * 32 + j * 8 + rB;
        int gc = (lane & 7) ^ (row & 7);
        bS[j] = Bf + (size_t)(n0 + row) * kKb + gc * 8;
    }
    const unsigned aDst = wave * 8192u;
    const unsigned bDst = 32768u + wave * 4096u;

    const int g = lane >> 4, rl = lane & 15;

    for (int t = 0; t < 16; ++t) {
        // ---- stage K-step t: A f32 (32 KB) + B f16 (16 KB)
#pragma unroll
        for (int j = 0; j < 8; ++j) gload16(aS[j] + t * 64, smem + aDst + j * 1024);
#pragma unroll
        for (int j = 0; j < 4; ++j) gload16(bS[j] + t * 64, smem + bDst + j * 1024);
        __syncthreads();   // drains vmcnt+lgkm, barrier
        // ---- compute: 2 kk x 16 MFMA; A cvt f32->f16 on the fragment path
#pragma unroll
        for (int kk = 0; kk < 2; ++kk) {
            f16x8 bfv[4];
#pragma unroll
            for (int ni = 0; ni < 4; ++ni)
                bfv[ni] = *(const f16x8*)(smem + 32768 + (wn * 64 + ni * 16 + rl) * 128
                                          + (((kk * 4 + g) ^ (rl & 7)) << 4));
#pragma unroll
            for (int mi = 0; mi < 4; ++mi) {
                const unsigned rowB = (unsigned)((wm * 64 + mi * 16 + rl) * 256);
                const int c = kk * 8 + g * 2;
                float4 lo = *(const float4*)(smem + rowB + ((c ^ rl) << 4));
                float4 hi = *(const float4*)(smem + rowB + (((c + 1) ^ rl) << 4));
                f16x8 ah;
                ah[0] = (f16)lo.x; ah[1] = (f16)lo.y; ah[2] = (f16)lo.z; ah[3] = (f16)lo.w;
                ah[4] = (f16)hi.x; ah[5] = (f16)hi.y; ah[6] = (f16)hi.z; ah[7] = (f16)hi.w;
                __builtin_amdgcn_s_setprio(1);
#pragma unroll
                for (int ni = 0; ni < 4; ++ni)
                    acc[mi][ni] = __builtin_amdgcn_mfma_f32_16x16x32_f16(ah, bfv[ni], acc[mi][ni], 0, 0, 0);
                __builtin_amdgcn_s_setprio(0);
            }
        }
        __syncthreads();
    }

    // ---- tail: loc @ U^T, K=32. A rows from locPad f16 (128B rows, XOR row&7);
    //      B cols 1024..1055 real U (+ zero pad). Single kk.
    {
#pragma unroll
        for (int j = 0; j < 4; ++j) {
            int row = wave * 32 + j * 8 + rB;
            int gc = (lane & 7) ^ (row & 7);
            const f16* tS = locPad + (size_t)(m0 + row) * 64 + gc * 8;
            gload16(tS, smem + wave * 4096u + j * 1024);
        }
#pragma unroll
        for (int j = 0; j < 4; ++j) gload16(bS[j] + 1024, smem + bDst + j * 1024);
        __syncthreads();
        f16x8 bfv[4];
#pragma unroll
        for (int ni = 0; ni < 4; ++ni)
            bfv[ni] = *(const f16x8*)(smem + 32768 + (wn * 64 + ni * 16 + rl) * 128
                                      + ((g ^ (rl & 7)) << 4));
        __builtin_amdgcn_s_setprio(1);
#pragma unroll
        for (int mi = 0; mi < 4; ++mi) {
            f16x8 ah = *(const f16x8*)(smem + (wm * 64 + mi * 16 + rl) * 128
                                       + ((g ^ (rl & 7)) << 4));
#pragma unroll
            for (int ni = 0; ni < 4; ++ni)
                acc[mi][ni] = __builtin_amdgcn_mfma_f32_16x16x32_f16(ah, bfv[ni], acc[mi][ni], 0, 0, 0);
        }
        __builtin_amdgcn_s_setprio(0);
        __syncthreads();
    }

    // ---- epilogue: e = tanh(acc + add[c]); partial score = sum_c e*w[c]
#pragma unroll
    for (int mi = 0; mi < 4; ++mi) {
#pragma unroll
        for (int i = 0; i < 4; ++i) {
            float p = 0.f;
#pragma unroll
            for (int ni = 0; ni < 4; ++ni) {
                int cl = wn * 64 + ni * 16 + rl;
                float e = tanhf(acc[mi][ni][i] + add_l[cl]);
                p += e * w_l[cl];
            }
            p += __shfl_xor(p, 1);
            p += __shfl_xor(p, 2);
            p += __shfl_xor(p, 4);
            p += __shfl_xor(p, 8);
            if (rl == 0) sred[wm][mi * 16 + g * 4 + i][wn] = p;
        }
    }
    __syncthreads();
    if (tid < 128) {
        int r = tid & 63, w2 = tid >> 6;
        float s = sred[w2][r][0] + sred[w2][r][1];
        spart[(size_t)nt * kM + m0 + tid] = s;
    }
}

// ---------------------------------------------------------------- softmax over T (8 partials)
__global__ void k_softmax(const float* __restrict__ spart, float* __restrict__ out_align) {
    __shared__ float red[256];
    int b = blockIdx.x, tid = threadIdx.x;
    float v[6];
    float mx = -1e30f;
#pragma unroll
    for (int i = 0; i < 6; ++i) {
        size_t idx = (size_t)b * kT + tid + i * 256;
        float s = 0.f;
#pragma unroll
        for (int p = 0; p < 8; ++p) s += spart[(size_t)p * kM + idx];
        v[i] = s; mx = fmaxf(mx, s);
    }
    red[tid] = mx; __syncthreads();
    for (int o = 128; o > 0; o >>= 1) { if (tid < o) red[tid] = fmaxf(red[tid], red[tid + o]); __syncthreads(); }
    mx = red[0]; __syncthreads();
    float sum = 0.f;
#pragma unroll
    for (int i = 0; i < 6; ++i) { v[i] = expf(v[i] - mx); sum += v[i]; }
    red[tid] = sum; __syncthreads();
    for (int o = 128; o > 0; o >>= 1) { if (tid < o) red[tid] += red[tid + o]; __syncthreads(); }
    float inv = 1.f / red[0];
#pragma unroll
    for (int i = 0; i < 6; ++i)
        out_align[(size_t)b * kT + tid + i * 256] = v[i] * inv;
}

// ---------------------------------------------------------------- context
__global__ void k_ctx_part(const float* __restrict__ enc, const float* __restrict__ align,
                           float* __restrict__ cpart) {
    __shared__ float al[192];
    int ci = blockIdx.x, b = blockIdx.y, tid = threadIdx.x;
    if (tid < 192) al[tid] = align[(size_t)b * kT + ci * 192 + tid];
    __syncthreads();
    float4 acc = {0.f, 0.f, 0.f, 0.f};
    const float* ep = enc + ((size_t)b * kT + (size_t)ci * 192) * kH + tid * 4;
    for (int t = 0; t < 192; ++t) {
        float a = al[t];
        float4 e = *(const float4*)(ep + (size_t)t * kH);
        acc.x += a * e.x; acc.y += a * e.y; acc.z += a * e.z; acc.w += a * e.w;
    }
    *(float4*)&cpart[((size_t)ci * kB + b) * kH + tid * 4] = acc;
}

__global__ void k_ctx_red(const float* __restrict__ cpart, float* __restrict__ out_ctx) {
    int idx = blockIdx.x * 256 + threadIdx.x;
    float s = 0.f;
#pragma unroll
    for (int ci = 0; ci < 8; ++ci) s += cpart[(size_t)ci * kB * kH + idx];
    out_ctx[idx] = s;
}

// ---------------------------------------------------------------- launch
extern "C" void kernel_launch(void* const* d_in, const int* in_sizes, int n_in,
                              void* d_out, int out_size, void* d_ws, size_t ws_size,
                              hipStream_t stream) {
    const float* dec  = (const float*)d_in[0];
    const float* enc  = (const float*)d_in[1];
    const float* la   = (const float*)d_in[2];
    const float* W    = (const float*)d_in[3];
    const float* V    = (const float*)d_in[4];
    const float* U    = (const float*)d_in[5];
    const float* bias = (const float*)d_in[6];
    const float* wv   = (const float*)d_in[7];
    const float* cw   = (const float*)d_in[8];
    const float* cb   = (const float*)d_in[9];

    char* ws = (char*)d_ws;
    f16* Bf      = (f16*)(ws + WS_B);
    f16* locPad  = (f16*)(ws + WS_LOC);
    float* add   = (float*)(ws + WS_ADD);
    float* spart = (float*)(ws + WS_SCORE);
    float* cpart = (float*)(ws + WS_CTXP);

    float* out_ctx   = (float*)d_out;            // (B,H)
    float* out_align = (float*)d_out + kB * kH;  // (B,T)

    hipLaunchKernelGGL(k_prep_b2,  dim3(kC),            dim3(256), 0, stream, V, U, Bf);
    hipLaunchKernelGGL(k_loc,      dim3(kM / 256),      dim3(256), 0, stream, la, cw, cb, locPad);
    hipLaunchKernelGGL(k_prep_add, dim3(kB * 4),        dim3(256), 0, stream, dec, W, bias, add);
    hipLaunchKernelGGL(k_main,     dim3((kM / 128) * 8), dim3(256), 0, stream, enc, Bf, locPad, add, wv, spart);
    hipLaunchKernelGGL(k_softmax,  dim3(kB),            dim3(256), 0, stream, spart, out_align);
    hipLaunchKernelGGL(k_ctx_part, dim3(8, kB),         dim3(256), 0, stream, enc, out_align, cpart);
    hipLaunchKernelGGL(k_ctx_red,  dim3(kB * kH / 256), dim3(256), 0, stream, cpart, out_ctx);
}